// Round 11
// baseline (271.612 us; speedup 1.0000x reference)
//
#include <hip/hip_runtime.h>
#include <hip/hip_bf16.h>
#include <stdint.h>

#define B_  4
#define S_  2048
#define H_  1024
#define NH_ 16
#define DK_ 64
#define M_  (B_*S_)   // 8192

typedef unsigned short u16;
typedef __attribute__((ext_vector_type(8))) short bfrag;     // 8 x bf16 (4 VGPRs)
typedef __attribute__((ext_vector_type(4))) float facc;      // 4 x f32
typedef __attribute__((ext_vector_type(16))) float f32x16;   // 32x32 accumulator
typedef __attribute__((ext_vector_type(4))) unsigned int u32x4;
typedef __attribute__((ext_vector_type(2))) unsigned int u32x2;

__device__ __forceinline__ u16 f2bf(float f) {
  uint32_t u = __float_as_uint(f);
  return (u16)((u + 0x7fffu + ((u >> 16) & 1u)) >> 16);    // RNE
}

__device__ __forceinline__ uint32_t cvtpk_bf16(float a, float b) {
  uint32_t r;
  asm("v_cvt_pk_bf16_f32 %0, %1, %2" : "=v"(r) : "v"(a), "v"(b));
  return r;
}

// ---------------- f32 -> bf16 convert: 3 activations in one launch ----------------
__global__ void cvt3_kernel(const float* __restrict__ a0, const float* __restrict__ a1,
                            const float* __restrict__ a2,
                            u16* __restrict__ o0, u16* __restrict__ o1, u16* __restrict__ o2,
                            int n4) {
  const float* in = blockIdx.y == 0 ? a0 : blockIdx.y == 1 ? a1 : a2;
  u16* out = blockIdx.y == 0 ? o0 : blockIdx.y == 1 ? o1 : o2;
  int i = blockIdx.x * blockDim.x + threadIdx.x;
  int stride = gridDim.x * blockDim.x;
  for (; i < n4; i += stride) {
    float4 v = reinterpret_cast<const float4*>(in)[i];
    ushort4 o;
    o.x = f2bf(v.x); o.y = f2bf(v.y); o.z = f2bf(v.z); o.w = f2bf(v.w);
    reinterpret_cast<ushort4*>(out)[i] = o;
  }
}

// ---------------- 4 weights in one launch; scale applied to y==0 (Wq) ----------------
__global__ void cvt4_kernel(const float* __restrict__ a0, const float* __restrict__ a1,
                            const float* __restrict__ a2, const float* __restrict__ a3,
                            u16* __restrict__ o0, u16* __restrict__ o1,
                            u16* __restrict__ o2, u16* __restrict__ o3,
                            int n4, float s0) {
  int y = blockIdx.y;
  const float* in = y == 0 ? a0 : y == 1 ? a1 : y == 2 ? a2 : a3;
  u16* out = y == 0 ? o0 : y == 1 ? o1 : y == 2 ? o2 : o3;
  float sc = (y == 0) ? s0 : 1.0f;
  int i = blockIdx.x * blockDim.x + threadIdx.x;
  int stride = gridDim.x * blockDim.x;
  for (; i < n4; i += stride) {
    float4 v = reinterpret_cast<const float4*>(in)[i];
    ushort4 o;
    o.x = f2bf(v.x * sc); o.y = f2bf(v.y * sc);
    o.z = f2bf(v.z * sc); o.w = f2bf(v.w * sc);
    reinterpret_cast<ushort4*>(out)[i] = o;
  }
}

// ---------------- mask int32 -> bf16 bias pairs in MFMA fragment order ----------------
// out dword (per bq,c,hl,cc,j): lo=bf16 bias for k-elem r=2j, hi=r=2j+1.
// bias = -8.0 (0xC100) unmasked, -inf (0xFF80) masked. C-init becomes shl/and.
__global__ void pack_mask_kernel(const int* __restrict__ m, uint32_t* __restrict__ out) {
  int od = blockIdx.x * blockDim.x + threadIdx.x;      // 0 .. B*S*1024-1
  int bq = od >> 10;
  int rem = od & 1023;
  int c = rem >> 5, t = rem & 31;
  int hl = t >> 4, cc = (t >> 3) & 1, j = t & 7;
  int bb = j >> 1, a = (j & 1) * 2;
  const int* p = m + (size_t)bq * 2048 + c*64 + 32*cc + 4*hl + 8*bb + a;
  int2 v = *reinterpret_cast<const int2*>(p);
  uint32_t lo = v.x ? 0xFF80u : 0xC100u;
  uint32_t hi = v.y ? 0xFF80u : 0xC100u;
  out[od] = lo | (hi << 16);
}

#define GLD16(gsrc, ldst) \
  __builtin_amdgcn_global_load_lds((const __attribute__((address_space(1))) void*)(gsrc), \
                                   (__attribute__((address_space(3))) void*)(ldst), 16, 0, 0)

// GEMM K-loop core, BK=64, XOR-swizzled LDS (pre-swizzled gload_lds source).
#define GEMM_KLOOP(A_, B_, As_, Bs_) \
  for (int k0 = 0; k0 < K; k0 += 64) { \
    const u16* Ab = (A_) + (size_t)m0 * K + k0; \
    const u16* Bb = (B_) + (size_t)n0 * K + k0; \
    _Pragma("unroll") \
    for (int i = 0; i < 4; i++) { \
      int idx = i*256 + tid; \
      int row = idx >> 3, q = idx & 7; \
      int qs = q ^ (row & 7); \
      char* la = (char*)(As_) + i*4096 + wave*1024; \
      char* lb = (char*)(Bs_) + i*4096 + wave*1024; \
      GLD16(Ab + (size_t)row*K + qs*8, la); \
      GLD16(Bb + (size_t)row*K + qs*8, lb); \
    } \
    __syncthreads(); \
    const int sa = (lo & 7) << 4; \
    _Pragma("unroll") \
    for (int kk = 0; kk < 2; kk++) { \
      bfrag af[4], bfv[4]; \
      _Pragma("unroll") \
      for (int t = 0; t < 4; t++) { \
        af[t]  = *reinterpret_cast<const bfrag*>((char*)(As_) + (wr*64 + t*16 + lo)*128 + ((kk*64 + hi*16) ^ sa)); \
        bfv[t] = *reinterpret_cast<const bfrag*>((char*)(Bs_) + (wc*64 + t*16 + lo)*128 + ((kk*64 + hi*16) ^ sa)); \
      } \
      _Pragma("unroll") \
      for (int mt = 0; mt < 4; mt++) \
        _Pragma("unroll") \
        for (int nt = 0; nt < 4; nt++) \
          acc[mt][nt] = __builtin_amdgcn_mfma_f32_16x16x32_bf16(af[mt], bfv[nt], acc[mt][nt], 0, 0, 0); \
    } \
    __syncthreads(); \
  }

// ---------------- Fused QKV projection GEMM ----------------
__global__ __launch_bounds__(256) void qkv_gemm(const u16* __restrict__ qa, const u16* __restrict__ ka,
                                                const u16* __restrict__ va,
                                                const u16* __restrict__ Wqb, const u16* __restrict__ Wkb,
                                                const u16* __restrict__ Wvb,
                                                const float* __restrict__ bqp, const float* __restrict__ bkp,
                                                const float* __restrict__ bvp, float qbscale,
                                                u16* __restrict__ qh, u16* __restrict__ kh,
                                                u16* __restrict__ vt) {
  constexpr int K = H_;
  __shared__ __align__(16) u16 SH[2][128*64];          // As / Bs, 16 KB each; SH[0] reused for V transpose
  u16* As = SH[0];
  u16* Bs = SH[1];
  const int tid = threadIdx.x;
  const int lane = tid & 63, wave = tid >> 6;
  const int lo = lane & 15, hi = lane >> 4;
  const int wr = wave >> 1, wc = wave & 1;
  const int wsel = blockIdx.y >> 3;
  const int m0 = blockIdx.x * 128, n0 = (blockIdx.y & 7) * 128;
  const u16* A  = wsel == 0 ? qa : wsel == 1 ? ka : va;
  const u16* Bm = wsel == 0 ? Wqb : wsel == 1 ? Wkb : Wvb;
  const float* bias = wsel == 0 ? bqp : wsel == 1 ? bkp : bvp;
  const float bscale = wsel == 0 ? qbscale : 1.0f;
  facc acc[4][4] = {};

  GEMM_KLOOP(A, Bm, As, Bs)

  if (wsel < 2) {
    u16* o = wsel == 0 ? qh : kh;
    #pragma unroll
    for (int nt = 0; nt < 4; nt++) {
      int n = n0 + wc*64 + nt*16 + lo;
      float bv = bias[n] * bscale;
      int hh = n >> 6, d = n & 63;
      #pragma unroll
      for (int mt = 0; mt < 4; mt++) {
        #pragma unroll
        for (int r = 0; r < 4; r++) {
          int m = m0 + wr*64 + mt*16 + hi*4 + r;
          int bb = m >> 11, s = m & (S_ - 1);
          o[(((size_t)bb*NH_ + hh)*S_ + s)*DK_ + d] = f2bf(acc[mt][nt][r] + bv);
        }
      }
    }
  } else {
    // V: tile -> LDS [64 d][128 s] (XOR-swizzled) -> coalesced d-major global writes.
    u16* scr = &SH[0][0];                     // 16 KB
    const int bb2 = m0 >> 11, s0r = m0 & (S_ - 1);
    #pragma unroll
    for (int p = 0; p < 2; p++) {            // head within n-range = wc
      __syncthreads();
      if (wc == p) {
        #pragma unroll
        for (int nt = 0; nt < 4; nt++) {
          int d = nt*16 + lo;
          float bv = bias[n0 + p*64 + d];
          #pragma unroll
          for (int mt = 0; mt < 4; mt++) {
            #pragma unroll
            for (int r = 0; r < 4; r++) {
              int s = wr*64 + mt*16 + hi*4 + r;
              *(u16*)((char*)scr + d*256 + ((s*2) ^ ((d & 7) << 4))) = f2bf(acc[mt][nt][r] + bv);
            }
          }
        }
      }
      __syncthreads();
      int hh = (n0 >> 6) + p;
      u16* vbase = vt + ((size_t)bb2*NH_ + hh) * DK_ * S_ + s0r;
      #pragma unroll
      for (int i = 0; i < 4; i++) {
        int idx = i*256 + tid;
        int d = idx >> 4, sc = idx & 15;
        bfrag v = *reinterpret_cast<const bfrag*>((char*)scr + d*256 + ((sc*16) ^ ((d & 7) << 4)));
        *reinterpret_cast<bfrag*>(vbase + (size_t)d*S_ + sc*8) = v;
      }
    }
  }
}

// ---------------- Output projection GEMM: out = xb @ Wo^T + bo (f32) ----------------
__global__ __launch_bounds__(256) void gemm_out(const u16* __restrict__ A, const u16* __restrict__ Bm,
                                                const float* __restrict__ bias, float* __restrict__ o) {
  constexpr int K = H_, N = H_;
  __shared__ __align__(16) u16 As[128*64];
  __shared__ __align__(16) u16 Bs[128*64];
  const int tid = threadIdx.x;
  const int lane = tid & 63, wave = tid >> 6;
  const int lo = lane & 15, hi = lane >> 4;
  const int wr = wave >> 1, wc = wave & 1;
  const int m0 = blockIdx.x * 128, n0 = blockIdx.y * 128;
  facc acc[4][4] = {};

  GEMM_KLOOP(A, Bm, As, Bs)

  #pragma unroll
  for (int nt = 0; nt < 4; nt++) {
    int n = n0 + wc*64 + nt*16 + lo;
    float bv = bias[n];
    #pragma unroll
    for (int mt = 0; mt < 4; mt++) {
      #pragma unroll
      for (int r = 0; r < 4; r++) {
        int m = m0 + wr*64 + mt*16 + hi*4 + r;
        o[(size_t)m*N + n] = acc[mt][nt][r] + bv;
      }
    }
  }
}

// ---------------- Flash attention v9 ----------------
// v7 + (1) bf16-bias mask: C-init = shl/and bit-moves (1 inst/elem, was 2);
// (2) denominator l computed on the MFMA pipe: acc_l = mfma(ones, pb, acc_l)
// — deletes the 23-add l-tree and the cross-half shuffle.
__global__ __launch_bounds__(256, 4) void attn_kernel(const u16* __restrict__ Qh, const u16* __restrict__ Kh,
                                                      const u16* __restrict__ Vt, const uint32_t* __restrict__ mbias,
                                                      u16* __restrict__ xout) {
  __shared__ __align__(16) u16 Ks[2][64*64];   // 8 KiB each, XOR-swizzled rows of 128 B
  __shared__ __align__(16) u16 Vs[2][64*64];
  const int tid = threadIdx.x;
  const int lane = tid & 63, wave = tid >> 6;
  const int l31 = lane & 31, hl = lane >> 5;
  const int gid = blockIdx.x;                  // XCD-bijective swizzle: 8 bh per XCD, qt inner
  const int bh = (gid & 7) * 8 + (gid >> 7);
  const int qt = (gid >> 3) & 15;
  const int b = bh >> 4, hd = bh & 15;
  const int q0 = qt * 128;
  const size_t bhS = (size_t)bh * S_;
  const int swz = (lane & 7) << 4;

  bfrag qf[4];
  {
    const u16* qrow = Qh + (bhS + q0 + wave*32 + l31) * DK_;
    #pragma unroll
    for (int t = 0; t < 4; t++) qf[t] = *reinterpret_cast<const bfrag*>(qrow + t*16 + hl*8);
  }
  // per-lane mask bias row: [q][c][hl][cc][8 dwords]; this lane reads 64 B/chunk at hl*64
  const char* mrowb = (const char*)mbias + ((size_t)b * S_ + q0 + wave*32 + l31) * 4096 + hl*64;

  const int srow = wave*8 + (lane >> 3);
  const int scol = ((lane & 7) ^ (lane >> 3)) * 16;
  const char* ksrc = (const char*)(Kh + bhS * DK_) + (size_t)srow * 128 + scol;
  const char* vsrc = (const char*)(Vt + (size_t)bh * DK_ * S_) + (size_t)srow * (S_*2) + scol;

#define STAGE(buf, c) { \
    char* kl = (char*)Ks[buf] + wave*1024; \
    char* vl = (char*)Vs[buf] + wave*1024; \
    GLD16(ksrc + (size_t)(c)*8192,          kl); \
    GLD16(ksrc + (size_t)(c)*8192 + 4096,   kl + 4096); \
    GLD16(vsrc + (size_t)(c)*128,           vl); \
    GLD16(vsrc + (size_t)(c)*128 + 131072,  vl + 4096); \
  }

  bfrag ones;
  #pragma unroll
  for (int j = 0; j < 8; j++) ones[j] = (short)0x3F80;   // bf16 1.0

  f32x16 accO[2], acc_l;
  #pragma unroll
  for (int e = 0; e < 16; e++) { accO[0][e] = 0.f; accO[1][e] = 0.f; acc_l[e] = 0.f; }

  STAGE(0, 0);
  u32x4 mA0_c = *reinterpret_cast<const u32x4*>(mrowb);
  u32x4 mA1_c = *reinterpret_cast<const u32x4*>(mrowb + 16);
  u32x4 mB0_c = *reinterpret_cast<const u32x4*>(mrowb + 32);
  u32x4 mB1_c = *reinterpret_cast<const u32x4*>(mrowb + 48);
  __syncthreads();

  for (int c = 0; c < 32; c++) {
    const int cur = c & 1;
    if (c + 1 < 32) STAGE(cur ^ 1, c + 1);

    u32x4 mA0 = mA0_c, mA1 = mA1_c, mB0 = mB0_c, mB1 = mB1_c;
    if (c + 1 < 32) {
      const char* mn = mrowb + (size_t)(c + 1)*128;
      mA0_c = *reinterpret_cast<const u32x4*>(mn);
      mA1_c = *reinterpret_cast<const u32x4*>(mn + 16);
      mB0_c = *reinterpret_cast<const u32x4*>(mn + 32);
      mB1_c = *reinterpret_cast<const u32x4*>(mn + 48);
    }

    // ---- C-init from bf16 bias pairs: s[2j] = w<<16, s[2j+1] = w & hi16 ----
    f32x16 s0, s1;
    #pragma unroll
    for (int j = 0; j < 8; j++) {
      uint32_t wA = (j < 4) ? mA0[j] : mA1[j - 4];
      uint32_t wB = (j < 4) ? mB0[j] : mB1[j - 4];
      s0[2*j]   = __builtin_bit_cast(float, wA << 16);
      s0[2*j+1] = __builtin_bit_cast(float, wA & 0xffff0000u);
      s1[2*j]   = __builtin_bit_cast(float, wB << 16);
      s1[2*j+1] = __builtin_bit_cast(float, wB & 0xffff0000u);
    }

    // ---- QK^T swapped ----
    const char* KsB = (const char*)Ks[cur];
    __builtin_amdgcn_s_setprio(1);
    #pragma unroll
    for (int t = 0; t < 4; t++) {
      bfrag k0 = *reinterpret_cast<const bfrag*>(KsB + l31*128        + ((t*32 + hl*16) ^ swz));
      bfrag k1 = *reinterpret_cast<const bfrag*>(KsB + (32 + l31)*128 + ((t*32 + hl*16) ^ swz));
      s0 = __builtin_amdgcn_mfma_f32_32x32x16_bf16(k0, qf[t], s0, 0, 0, 0);
      s1 = __builtin_amdgcn_mfma_f32_32x32x16_bf16(k1, qf[t], s1, 0, 0, 0);
    }
    __builtin_amdgcn_s_setprio(0);

    // ---- p = 2^s directly (bias already in C); masked (-inf) -> exactly 0 ----
    #pragma unroll
    for (int r = 0; r < 16; r++) {
      s0[r] = __builtin_amdgcn_exp2f(s0[r]);
      s1[r] = __builtin_amdgcn_exp2f(s1[r]);
    }

    // ---- P -> PV A-frags in-register ----
    u32x4 pa[4];
    #pragma unroll
    for (int kt = 0; kt < 2; kt++) {
      uint32_t W[8];
      #pragma unroll
      for (int j = 0; j < 8; j++)
        W[j] = kt == 0 ? cvtpk_bf16(s0[2*j], s0[2*j+1]) : cvtpk_bf16(s1[2*j], s1[2*j+1]);
      u32x2 r02 = __builtin_amdgcn_permlane32_swap(W[0], W[2], false, false);
      u32x2 r13 = __builtin_amdgcn_permlane32_swap(W[1], W[3], false, false);
      u32x2 r46 = __builtin_amdgcn_permlane32_swap(W[4], W[6], false, false);
      u32x2 r57 = __builtin_amdgcn_permlane32_swap(W[5], W[7], false, false);
      pa[kt*2    ][0] = r02[0]; pa[kt*2    ][1] = r13[0]; pa[kt*2    ][2] = r02[1]; pa[kt*2    ][3] = r13[1];
      pa[kt*2 + 1][0] = r46[0]; pa[kt*2 + 1][1] = r57[0]; pa[kt*2 + 1][2] = r46[1]; pa[kt*2 + 1][3] = r57[1];
    }

    // ---- PV + denominator on the MFMA pipe ----
    const char* VsB = (const char*)Vs[cur];
    __builtin_amdgcn_s_setprio(1);
    #pragma unroll
    for (int ks = 0; ks < 4; ks++) {
      bfrag pb = __builtin_bit_cast(bfrag, pa[ks]);
      bfrag v0 = *reinterpret_cast<const bfrag*>(VsB + l31*128        + ((ks*32 + hl*16) ^ swz));
      bfrag v1 = *reinterpret_cast<const bfrag*>(VsB + (32 + l31)*128 + ((ks*32 + hl*16) ^ swz));
      accO[0] = __builtin_amdgcn_mfma_f32_32x32x16_bf16(v0, pb, accO[0], 0, 0, 0);
      accO[1] = __builtin_amdgcn_mfma_f32_32x32x16_bf16(v1, pb, accO[1], 0, 0, 0);
      acc_l   = __builtin_amdgcn_mfma_f32_32x32x16_bf16(ones, pb, acc_l, 0, 0, 0);
    }
    __builtin_amdgcn_s_setprio(0);
    __syncthreads();
  }
#undef STAGE

  // ---- finalize: acc_l[0] is the full denominator for this lane's q ----
  float l_tot = acc_l[0];
  float linv = (l_tot > 0.f) ? (1.f / l_tot) : 0.f;
  u16* Xs = (u16*)Ks;
  {
    char* xb = (char*)Xs + (wave*32 + l31) * 128;
    #pragma unroll
    for (int dt = 0; dt < 2; dt++)
      #pragma unroll
      for (int j = 0; j < 8; j++) {
        uint32_t w = cvtpk_bf16(accO[dt][2*j] * linv, accO[dt][2*j+1] * linv);
        int d = dt*32 + ((2*j) & 3) + 8*((2*j) >> 2) + 4*hl;
        *reinterpret_cast<uint32_t*>(xb + ((d*2) ^ swz)) = w;
      }
  }
  __syncthreads();
  {
    int row = tid >> 1, d0 = (tid & 1) * 32;
    int rsw = (row & 7) << 4;
    u16* orow = xout + ((size_t)b * S_ + q0 + row) * H_ + hd * DK_ + d0;
    #pragma unroll
    for (int i = 0; i < 4; i++) {
      bfrag v = *reinterpret_cast<const bfrag*>((char*)Xs + row*128 + ((d0*2 + i*16) ^ rsw));
      *reinterpret_cast<bfrag*>((char*)orow + i*16) = v;
    }
  }
}

// ---------------- launch ----------------
extern "C" void kernel_launch(void* const* d_in, const int* in_sizes, int n_in,
                              void* d_out, int out_size, void* d_ws, size_t ws_size,
                              hipStream_t stream) {
  const float* query = (const float*)d_in[0];
  const float* key_  = (const float*)d_in[1];
  const float* value = (const float*)d_in[2];
  const int*   mask  = (const int*)d_in[3];
  const float* Wq = (const float*)d_in[4];
  const float* bq = (const float*)d_in[5];
  const float* Wk = (const float*)d_in[6];
  const float* bk = (const float*)d_in[7];
  const float* Wv = (const float*)d_in[8];
  const float* bv = (const float*)d_in[9];
  const float* Wo = (const float*)d_in[10];
  const float* bo = (const float*)d_in[11];
  float* out = (float*)d_out;

  char* ws = (char*)d_ws;
  const size_t MB = 1024 * 1024;
  u16* q_act = (u16*)(ws + 0*MB);     // 16 MiB each
  u16* k_act = (u16*)(ws + 16*MB);
  u16* v_act = (u16*)(ws + 32*MB);
  u16* wq_b  = (u16*)(ws + 48*MB);    // 2 MiB each
  u16* wk_b  = (u16*)(ws + 50*MB);
  u16* wv_b  = (u16*)(ws + 52*MB);
  u16* wo_b  = (u16*)(ws + 54*MB);
  u16* qh    = (u16*)(ws + 56*MB);
  u16* kh    = (u16*)(ws + 72*MB);
  u16* vt    = (u16*)(ws + 88*MB);
  u16* xb    = (u16*)(ws + 104*MB);
  uint32_t* mbias = (uint32_t*)(ws + 120*MB);   // 33.6 MiB bf16 bias pairs (fragment order)

  const float QSCALE = 0.125f * 1.44269504088896f;   // 1/sqrt(DK) * log2(e), folded into Wq/bq

  const int nact4 = M_ * H_ / 4;
  cvt3_kernel<<<dim3(1024, 3), 256, 0, stream>>>(query, key_, value, q_act, k_act, v_act, nact4);
  const int nw4 = H_ * H_ / 4;
  cvt4_kernel<<<dim3(256, 4), 256, 0, stream>>>(Wq, Wk, Wv, Wo, wq_b, wk_b, wv_b, wo_b, nw4, QSCALE);
  const int ndwords = B_ * S_ * 1024;                // 8,388,608
  pack_mask_kernel<<<ndwords/256, 256, 0, stream>>>(mask, mbias);

  qkv_gemm<<<dim3(M_/128, 24), 256, 0, stream>>>(q_act, k_act, v_act, wq_b, wk_b, wv_b,
                                                 bq, bk, bv, QSCALE, qh, kh, vt);
  attn_kernel<<<1024, 256, 0, stream>>>(qh, kh, vt, mbias, xb);
  gemm_out<<<dim3(M_/128, H_/128), 256, 0, stream>>>(xb, wo_b, bo, out);
}

// Round 12
// 239.607 us; speedup vs baseline: 1.1336x; 1.1336x over previous
//
#include <hip/hip_runtime.h>
#include <hip/hip_bf16.h>
#include <stdint.h>

#define B_  4
#define S_  2048
#define H_  1024
#define NH_ 16
#define DK_ 64
#define M_  (B_*S_)   // 8192

typedef unsigned short u16;
typedef __attribute__((ext_vector_type(8))) short bfrag;     // 8 x bf16 (4 VGPRs)
typedef __attribute__((ext_vector_type(4))) float facc;      // 4 x f32
typedef __attribute__((ext_vector_type(16))) float f32x16;   // 32x32 accumulator
typedef __attribute__((ext_vector_type(4))) unsigned int u32x4;
typedef __attribute__((ext_vector_type(2))) unsigned int u32x2;

__device__ __forceinline__ u16 f2bf(float f) {
  uint32_t u = __float_as_uint(f);
  return (u16)((u + 0x7fffu + ((u >> 16) & 1u)) >> 16);    // RNE
}

__device__ __forceinline__ uint32_t cvtpk_bf16(float a, float b) {
  uint32_t r;
  asm("v_cvt_pk_bf16_f32 %0, %1, %2" : "=v"(r) : "v"(a), "v"(b));
  return r;
}

// ---------------- f32 -> bf16 convert: 3 activations in one launch ----------------
__global__ void cvt3_kernel(const float* __restrict__ a0, const float* __restrict__ a1,
                            const float* __restrict__ a2,
                            u16* __restrict__ o0, u16* __restrict__ o1, u16* __restrict__ o2,
                            int n4) {
  const float* in = blockIdx.y == 0 ? a0 : blockIdx.y == 1 ? a1 : a2;
  u16* out = blockIdx.y == 0 ? o0 : blockIdx.y == 1 ? o1 : o2;
  int i = blockIdx.x * blockDim.x + threadIdx.x;
  int stride = gridDim.x * blockDim.x;
  for (; i < n4; i += stride) {
    float4 v = reinterpret_cast<const float4*>(in)[i];
    ushort4 o;
    o.x = f2bf(v.x); o.y = f2bf(v.y); o.z = f2bf(v.z); o.w = f2bf(v.w);
    reinterpret_cast<ushort4*>(out)[i] = o;
  }
}

// ---------------- 4 weights in one launch; scale applied to y==0 (Wq) ----------------
__global__ void cvt4_kernel(const float* __restrict__ a0, const float* __restrict__ a1,
                            const float* __restrict__ a2, const float* __restrict__ a3,
                            u16* __restrict__ o0, u16* __restrict__ o1,
                            u16* __restrict__ o2, u16* __restrict__ o3,
                            int n4, float s0) {
  int y = blockIdx.y;
  const float* in = y == 0 ? a0 : y == 1 ? a1 : y == 2 ? a2 : a3;
  u16* out = y == 0 ? o0 : y == 1 ? o1 : y == 2 ? o2 : o3;
  float sc = (y == 0) ? s0 : 1.0f;
  int i = blockIdx.x * blockDim.x + threadIdx.x;
  int stride = gridDim.x * blockDim.x;
  for (; i < n4; i += stride) {
    float4 v = reinterpret_cast<const float4*>(in)[i];
    ushort4 o;
    o.x = f2bf(v.x * sc); o.y = f2bf(v.y * sc);
    o.z = f2bf(v.z * sc); o.w = f2bf(v.w * sc);
    reinterpret_cast<ushort4*>(out)[i] = o;
  }
}

// ---------------- mask int32 -> bytes, COALESCED layout ----------------
// dword content identical to v7 (byte=1 if masked, fragment order), but output
// address is [qblk][c][wave][hl][l31][j]: a wave's per-chunk mask reads span one
// contiguous 2 KB block (was: 16-B loads at 2 KB lane stride = 64 lines/load).
__global__ void pack_mask_kernel(const int* __restrict__ m, uint32_t* __restrict__ out) {
  int od = blockIdx.x * blockDim.x + threadIdx.x;      // 0 .. B*S*512-1
  int bq = od >> 9;
  int rem = od & 511;
  int c = rem >> 4, t = rem & 15;
  int hl = t >> 3, cc = (t >> 2) & 1, bb = t & 3;
  int4 v = *reinterpret_cast<const int4*>(m + (size_t)bq * 2048 + c*64 + 4*hl + 8*bb + 32*cc);
  uint32_t w = (v.x != 0 ? 1u : 0u) | (v.y != 0 ? 0x100u : 0u) |
               (v.z != 0 ? 0x10000u : 0u) | (v.w != 0 ? 0x1000000u : 0u);
  int qblk = bq >> 7, qin = bq & 127;
  int wv = qin >> 5, l31q = qin & 31;
  int j = cc*4 + bb;
  size_t nod = (size_t)qblk*65536 + c*2048 + wv*512 + hl*256 + l31q*8 + j;
  out[nod] = w;
}

#define GLD16(gsrc, ldst) \
  __builtin_amdgcn_global_load_lds((const __attribute__((address_space(1))) void*)(gsrc), \
                                   (__attribute__((address_space(3))) void*)(ldst), 16, 0, 0)

// GEMM K-loop core, BK=64, XOR-swizzled LDS (pre-swizzled gload_lds source).
#define GEMM_KLOOP(A_, B_, As_, Bs_) \
  for (int k0 = 0; k0 < K; k0 += 64) { \
    const u16* Ab = (A_) + (size_t)m0 * K + k0; \
    const u16* Bb = (B_) + (size_t)n0 * K + k0; \
    _Pragma("unroll") \
    for (int i = 0; i < 4; i++) { \
      int idx = i*256 + tid; \
      int row = idx >> 3, q = idx & 7; \
      int qs = q ^ (row & 7); \
      char* la = (char*)(As_) + i*4096 + wave*1024; \
      char* lb = (char*)(Bs_) + i*4096 + wave*1024; \
      GLD16(Ab + (size_t)row*K + qs*8, la); \
      GLD16(Bb + (size_t)row*K + qs*8, lb); \
    } \
    __syncthreads(); \
    const int sa = (lo & 7) << 4; \
    _Pragma("unroll") \
    for (int kk = 0; kk < 2; kk++) { \
      bfrag af[4], bfv[4]; \
      _Pragma("unroll") \
      for (int t = 0; t < 4; t++) { \
        af[t]  = *reinterpret_cast<const bfrag*>((char*)(As_) + (wr*64 + t*16 + lo)*128 + ((kk*64 + hi*16) ^ sa)); \
        bfv[t] = *reinterpret_cast<const bfrag*>((char*)(Bs_) + (wc*64 + t*16 + lo)*128 + ((kk*64 + hi*16) ^ sa)); \
      } \
      _Pragma("unroll") \
      for (int mt = 0; mt < 4; mt++) \
        _Pragma("unroll") \
        for (int nt = 0; nt < 4; nt++) \
          acc[mt][nt] = __builtin_amdgcn_mfma_f32_16x16x32_bf16(af[mt], bfv[nt], acc[mt][nt], 0, 0, 0); \
    } \
    __syncthreads(); \
  }

// ---------------- Fused QKV projection GEMM ----------------
__global__ __launch_bounds__(256) void qkv_gemm(const u16* __restrict__ qa, const u16* __restrict__ ka,
                                                const u16* __restrict__ va,
                                                const u16* __restrict__ Wqb, const u16* __restrict__ Wkb,
                                                const u16* __restrict__ Wvb,
                                                const float* __restrict__ bqp, const float* __restrict__ bkp,
                                                const float* __restrict__ bvp, float qbscale,
                                                u16* __restrict__ qh, u16* __restrict__ kh,
                                                u16* __restrict__ vt) {
  constexpr int K = H_;
  __shared__ __align__(16) u16 SH[2][128*64];          // As / Bs, 16 KB each; SH[0] reused for V transpose
  u16* As = SH[0];
  u16* Bs = SH[1];
  const int tid = threadIdx.x;
  const int lane = tid & 63, wave = tid >> 6;
  const int lo = lane & 15, hi = lane >> 4;
  const int wr = wave >> 1, wc = wave & 1;
  const int wsel = blockIdx.y >> 3;
  const int m0 = blockIdx.x * 128, n0 = (blockIdx.y & 7) * 128;
  const u16* A  = wsel == 0 ? qa : wsel == 1 ? ka : va;
  const u16* Bm = wsel == 0 ? Wqb : wsel == 1 ? Wkb : Wvb;
  const float* bias = wsel == 0 ? bqp : wsel == 1 ? bkp : bvp;
  const float bscale = wsel == 0 ? qbscale : 1.0f;
  facc acc[4][4] = {};

  GEMM_KLOOP(A, Bm, As, Bs)

  if (wsel < 2) {
    u16* o = wsel == 0 ? qh : kh;
    #pragma unroll
    for (int nt = 0; nt < 4; nt++) {
      int n = n0 + wc*64 + nt*16 + lo;
      float bv = bias[n] * bscale;
      int hh = n >> 6, d = n & 63;
      #pragma unroll
      for (int mt = 0; mt < 4; mt++) {
        #pragma unroll
        for (int r = 0; r < 4; r++) {
          int m = m0 + wr*64 + mt*16 + hi*4 + r;
          int bb = m >> 11, s = m & (S_ - 1);
          o[(((size_t)bb*NH_ + hh)*S_ + s)*DK_ + d] = f2bf(acc[mt][nt][r] + bv);
        }
      }
    }
  } else {
    // V: tile -> LDS [64 d][128 s] (XOR-swizzled) -> coalesced d-major global writes.
    u16* scr = &SH[0][0];                     // 16 KB
    const int bb2 = m0 >> 11, s0r = m0 & (S_ - 1);
    #pragma unroll
    for (int p = 0; p < 2; p++) {            // head within n-range = wc
      __syncthreads();
      if (wc == p) {
        #pragma unroll
        for (int nt = 0; nt < 4; nt++) {
          int d = nt*16 + lo;
          float bv = bias[n0 + p*64 + d];
          #pragma unroll
          for (int mt = 0; mt < 4; mt++) {
            #pragma unroll
            for (int r = 0; r < 4; r++) {
              int s = wr*64 + mt*16 + hi*4 + r;
              *(u16*)((char*)scr + d*256 + ((s*2) ^ ((d & 7) << 4))) = f2bf(acc[mt][nt][r] + bv);
            }
          }
        }
      }
      __syncthreads();
      int hh = (n0 >> 6) + p;
      u16* vbase = vt + ((size_t)bb2*NH_ + hh) * DK_ * S_ + s0r;
      #pragma unroll
      for (int i = 0; i < 4; i++) {
        int idx = i*256 + tid;
        int d = idx >> 4, sc = idx & 15;
        bfrag v = *reinterpret_cast<const bfrag*>((char*)scr + d*256 + ((sc*16) ^ ((d & 7) << 4)));
        *reinterpret_cast<bfrag*>(vbase + (size_t)d*S_ + sc*8) = v;
      }
    }
  }
}

// ---------------- Output projection GEMM: out = xb @ Wo^T + bo (f32) ----------------
__global__ __launch_bounds__(256) void gemm_out(const u16* __restrict__ A, const u16* __restrict__ Bm,
                                                const float* __restrict__ bias, float* __restrict__ o) {
  constexpr int K = H_, N = H_;
  __shared__ __align__(16) u16 As[128*64];
  __shared__ __align__(16) u16 Bs[128*64];
  const int tid = threadIdx.x;
  const int lane = tid & 63, wave = tid >> 6;
  const int lo = lane & 15, hi = lane >> 4;
  const int wr = wave >> 1, wc = wave & 1;
  const int m0 = blockIdx.x * 128, n0 = blockIdx.y * 128;
  facc acc[4][4] = {};

  GEMM_KLOOP(A, Bm, As, Bs)

  #pragma unroll
  for (int nt = 0; nt < 4; nt++) {
    int n = n0 + wc*64 + nt*16 + lo;
    float bv = bias[n];
    #pragma unroll
    for (int mt = 0; mt < 4; mt++) {
      #pragma unroll
      for (int r = 0; r < 4; r++) {
        int m = m0 + wr*64 + mt*16 + hi*4 + r;
        o[(size_t)m*N + n] = acc[mt][nt][r] + bv;
      }
    }
  }
}

// ---------------- Flash attention v7c: fixed-M softmax, coalesced mask reads ----------------
__global__ __launch_bounds__(256, 4) void attn_kernel(const u16* __restrict__ Qh, const u16* __restrict__ Kh,
                                                      const u16* __restrict__ Vt, const uint32_t* __restrict__ mbytes,
                                                      u16* __restrict__ xout) {
  __shared__ __align__(16) u16 Ks[2][64*64];   // 8 KiB each, XOR-swizzled rows of 128 B
  __shared__ __align__(16) u16 Vs[2][64*64];
  const int tid = threadIdx.x;
  const int lane = tid & 63, wave = tid >> 6;
  const int l31 = lane & 31, hl = lane >> 5;
  const int gid = blockIdx.x;                  // XCD-bijective swizzle: 8 bh per XCD, qt inner
  const int bh = (gid & 7) * 8 + (gid >> 7);
  const int qt = (gid >> 3) & 15;
  const int b = bh >> 4, hd = bh & 15;
  const int q0 = qt * 128;
  const size_t bhS = (size_t)bh * S_;
  const int swz = (lane & 7) << 4;

  bfrag qf[4];
  {
    const u16* qrow = Qh + (bhS + q0 + wave*32 + l31) * DK_;
    #pragma unroll
    for (int t = 0; t < 4; t++) qf[t] = *reinterpret_cast<const bfrag*>(qrow + t*16 + hl*8);
  }
  // coalesced mask base: [qblk][c][wave][hl][l31][32B]; wave's chunk-read = contiguous 2 KB
  const int qblk = b*16 + qt;
  const char* mrowb = (const char*)mbytes + (size_t)qblk*262144 + wave*2048 + hl*1024 + l31*32;

  const int srow = wave*8 + (lane >> 3);
  const int scol = ((lane & 7) ^ (lane >> 3)) * 16;
  const char* ksrc = (const char*)(Kh + bhS * DK_) + (size_t)srow * 128 + scol;
  const char* vsrc = (const char*)(Vt + (size_t)bh * DK_ * S_) + (size_t)srow * (S_*2) + scol;

#define STAGE(buf, c) { \
    char* kl = (char*)Ks[buf] + wave*1024; \
    char* vl = (char*)Vs[buf] + wave*1024; \
    GLD16(ksrc + (size_t)(c)*8192,          kl); \
    GLD16(ksrc + (size_t)(c)*8192 + 4096,   kl + 4096); \
    GLD16(vsrc + (size_t)(c)*128,           vl); \
    GLD16(vsrc + (size_t)(c)*128 + 131072,  vl + 4096); \
  }

  float l_run = 0.f;                           // per-half-lane partial denominator
  f32x16 accO[2];
  #pragma unroll
  for (int e = 0; e < 16; e++) { accO[0][e] = 0.f; accO[1][e] = 0.f; }

  STAGE(0, 0);
  u32x4 mA_cur = *reinterpret_cast<const u32x4*>(mrowb);
  u32x4 mB_cur = *reinterpret_cast<const u32x4*>(mrowb + 16);
  __syncthreads();

  for (int c = 0; c < 32; c++) {
    const int cur = c & 1;
    if (c + 1 < 32) STAGE(cur ^ 1, c + 1);

    u32x4 mA = mA_cur, mB = mB_cur;
    if (c + 1 < 32) {
      const char* mn = mrowb + (size_t)(c + 1)*8192;
      mA_cur = *reinterpret_cast<const u32x4*>(mn);
      mB_cur = *reinterpret_cast<const u32x4*>(mn + 16);
    }

    // ---- C-init = -M - 1e36*maskbyte ----
    f32x16 s0, s1;
    #pragma unroll
    for (int r = 0; r < 16; r++) {
      float f0 = (float)((mA[r >> 2] >> ((r & 3) * 8)) & 0xffu);
      float f1 = (float)((mB[r >> 2] >> ((r & 3) * 8)) & 0xffu);
      s0[r] = __builtin_fmaf(f0, -1e36f, -8.0f);
      s1[r] = __builtin_fmaf(f1, -1e36f, -8.0f);
    }

    // ---- QK^T swapped ----
    const char* KsB = (const char*)Ks[cur];
    __builtin_amdgcn_s_setprio(1);
    #pragma unroll
    for (int t = 0; t < 4; t++) {
      bfrag k0 = *reinterpret_cast<const bfrag*>(KsB + l31*128        + ((t*32 + hl*16) ^ swz));
      bfrag k1 = *reinterpret_cast<const bfrag*>(KsB + (32 + l31)*128 + ((t*32 + hl*16) ^ swz));
      s0 = __builtin_amdgcn_mfma_f32_32x32x16_bf16(k0, qf[t], s0, 0, 0, 0);
      s1 = __builtin_amdgcn_mfma_f32_32x32x16_bf16(k1, qf[t], s1, 0, 0, 0);
    }
    __builtin_amdgcn_s_setprio(0);

    // ---- p = 2^s directly ----
    #pragma unroll
    for (int r = 0; r < 16; r++) {
      s0[r] = __builtin_amdgcn_exp2f(s0[r]);
      s1[r] = __builtin_amdgcn_exp2f(s1[r]);
    }
    float a8[8];
    #pragma unroll
    for (int r = 0; r < 8; r++) a8[r] = (s0[r] + s0[r+8]) + (s1[r] + s1[r+8]);
    l_run += ((a8[0] + a8[1]) + (a8[2] + a8[3])) + ((a8[4] + a8[5]) + (a8[6] + a8[7]));

    // ---- P -> PV A-frags in-register ----
    u32x4 pa[4];
    #pragma unroll
    for (int kt = 0; kt < 2; kt++) {
      uint32_t W[8];
      #pragma unroll
      for (int j = 0; j < 8; j++)
        W[j] = kt == 0 ? cvtpk_bf16(s0[2*j], s0[2*j+1]) : cvtpk_bf16(s1[2*j], s1[2*j+1]);
      u32x2 r02 = __builtin_amdgcn_permlane32_swap(W[0], W[2], false, false);
      u32x2 r13 = __builtin_amdgcn_permlane32_swap(W[1], W[3], false, false);
      u32x2 r46 = __builtin_amdgcn_permlane32_swap(W[4], W[6], false, false);
      u32x2 r57 = __builtin_amdgcn_permlane32_swap(W[5], W[7], false, false);
      pa[kt*2    ][0] = r02[0]; pa[kt*2    ][1] = r13[0]; pa[kt*2    ][2] = r02[1]; pa[kt*2    ][3] = r13[1];
      pa[kt*2 + 1][0] = r46[0]; pa[kt*2 + 1][1] = r57[0]; pa[kt*2 + 1][2] = r46[1]; pa[kt*2 + 1][3] = r57[1];
    }

    // ---- PV ----
    const char* VsB = (const char*)Vs[cur];
    __builtin_amdgcn_s_setprio(1);
    #pragma unroll
    for (int ks = 0; ks < 4; ks++) {
      bfrag pb = __builtin_bit_cast(bfrag, pa[ks]);
      bfrag v0 = *reinterpret_cast<const bfrag*>(VsB + l31*128        + ((ks*32 + hl*16) ^ swz));
      bfrag v1 = *reinterpret_cast<const bfrag*>(VsB + (32 + l31)*128 + ((ks*32 + hl*16) ^ swz));
      accO[0] = __builtin_amdgcn_mfma_f32_32x32x16_bf16(v0, pb, accO[0], 0, 0, 0);
      accO[1] = __builtin_amdgcn_mfma_f32_32x32x16_bf16(v1, pb, accO[1], 0, 0, 0);
    }
    __builtin_amdgcn_s_setprio(0);
    __syncthreads();
  }
#undef STAGE

  // ---- finalize ----
  float l_tot = l_run + __shfl_xor(l_run, 32);
  float linv = (l_tot > 0.f) ? (1.f / l_tot) : 0.f;
  u16* Xs = (u16*)Ks;
  {
    char* xb = (char*)Xs + (wave*32 + l31) * 128;
    #pragma unroll
    for (int dt = 0; dt < 2; dt++)
      #pragma unroll
      for (int j = 0; j < 8; j++) {
        uint32_t w = cvtpk_bf16(accO[dt][2*j] * linv, accO[dt][2*j+1] * linv);
        int d = dt*32 + ((2*j) & 3) + 8*((2*j) >> 2) + 4*hl;
        *reinterpret_cast<uint32_t*>(xb + ((d*2) ^ swz)) = w;
      }
  }
  __syncthreads();
  {
    int row = tid >> 1, d0 = (tid & 1) * 32;
    int rsw = (row & 7) << 4;
    u16* orow = xout + ((size_t)b * S_ + q0 + row) * H_ + hd * DK_ + d0;
    #pragma unroll
    for (int i = 0; i < 4; i++) {
      bfrag v = *reinterpret_cast<const bfrag*>((char*)Xs + row*128 + ((d0*2 + i*16) ^ rsw));
      *reinterpret_cast<bfrag*>((char*)orow + i*16) = v;
    }
  }
}

// ---------------- launch ----------------
extern "C" void kernel_launch(void* const* d_in, const int* in_sizes, int n_in,
                              void* d_out, int out_size, void* d_ws, size_t ws_size,
                              hipStream_t stream) {
  const float* query = (const float*)d_in[0];
  const float* key_  = (const float*)d_in[1];
  const float* value = (const float*)d_in[2];
  const int*   mask  = (const int*)d_in[3];
  const float* Wq = (const float*)d_in[4];
  const float* bq = (const float*)d_in[5];
  const float* Wk = (const float*)d_in[6];
  const float* bk = (const float*)d_in[7];
  const float* Wv = (const float*)d_in[8];
  const float* bv = (const float*)d_in[9];
  const float* Wo = (const float*)d_in[10];
  const float* bo = (const float*)d_in[11];
  float* out = (float*)d_out;

  char* ws = (char*)d_ws;
  const size_t MB = 1024 * 1024;
  u16* q_act = (u16*)(ws + 0*MB);
  u16* k_act = (u16*)(ws + 16*MB);
  u16* v_act = (u16*)(ws + 32*MB);
  u16* wq_b  = (u16*)(ws + 48*MB);
  u16* wk_b  = (u16*)(ws + 50*MB);
  u16* wv_b  = (u16*)(ws + 52*MB);
  u16* wo_b  = (u16*)(ws + 54*MB);
  u16* qh    = (u16*)(ws + 56*MB);
  u16* kh    = (u16*)(ws + 72*MB);
  u16* vt    = (u16*)(ws + 104*MB);
  u16* xb    = (u16*)(ws + 120*MB);
  uint32_t* mbytes = (uint32_t*)(ws + 136*MB);   // 16.8 MiB mask bytes (coalesced layout)

  const float QSCALE = 0.125f * 1.44269504088896f;   // 1/sqrt(DK) * log2(e), folded into Wq/bq

  const int nact4 = M_ * H_ / 4;
  cvt3_kernel<<<dim3(1024, 3), 256, 0, stream>>>(query, key_, value, q_act, k_act, v_act, nact4);
  const int nw4 = H_ * H_ / 4;
  cvt4_kernel<<<dim3(256, 4), 256, 0, stream>>>(Wq, Wk, Wv, Wo, wq_b, wk_b, wv_b, wo_b, nw4, QSCALE);
  const int ndwords = B_ * S_ * 512;                 // 4,194,304
  pack_mask_kernel<<<ndwords/256, 256, 0, stream>>>(mask, mbytes);

  qkv_gemm<<<dim3(M_/128, 24), 256, 0, stream>>>(q_act, k_act, v_act, wq_b, wk_b, wv_b,
                                                 bq, bk, bv, QSCALE, qh, kh, vt);
  attn_kernel<<<1024, 256, 0, stream>>>(qh, kh, vt, mbytes, xb);
  gemm_out<<<dim3(M_/128, H_/128), 256, 0, stream>>>(xb, wo_b, bo, out);
}

// Round 13
// 228.992 us; speedup vs baseline: 1.1861x; 1.0464x over previous
//
#include <hip/hip_runtime.h>
#include <hip/hip_bf16.h>
#include <stdint.h>

#define B_  4
#define S_  2048
#define H_  1024
#define NH_ 16
#define DK_ 64
#define M_  (B_*S_)   // 8192

typedef unsigned short u16;
typedef __attribute__((ext_vector_type(8))) short bfrag;     // 8 x bf16 (4 VGPRs)
typedef __attribute__((ext_vector_type(4))) float facc;      // 4 x f32
typedef __attribute__((ext_vector_type(16))) float f32x16;   // 32x32 accumulator
typedef __attribute__((ext_vector_type(4))) unsigned int u32x4;
typedef __attribute__((ext_vector_type(2))) unsigned int u32x2;

__device__ __forceinline__ u16 f2bf(float f) {
  uint32_t u = __float_as_uint(f);
  return (u16)((u + 0x7fffu + ((u >> 16) & 1u)) >> 16);    // RNE
}

__device__ __forceinline__ uint32_t cvtpk_bf16(float a, float b) {
  uint32_t r;
  asm("v_cvt_pk_bf16_f32 %0, %1, %2" : "=v"(r) : "v"(a), "v"(b));
  return r;
}

// ---------------- Fused prep: activation cvt (3) + weight cvt (4) + mask pack ----------------
// blocks [0,3072): activations; [3072,4096): weights; [4096,20480): mask pack (gather,
// linear coalesced writes — R12's scatter-write form cost ~9 µs in store fan-out).
__global__ __launch_bounds__(256) void prep_kernel(
    const float* __restrict__ qa, const float* __restrict__ ka, const float* __restrict__ va,
    const float* __restrict__ Wq, const float* __restrict__ Wk,
    const float* __restrict__ Wv, const float* __restrict__ Wo,
    const int* __restrict__ mask,
    u16* __restrict__ qo, u16* __restrict__ ko, u16* __restrict__ vo,
    u16* __restrict__ wqo, u16* __restrict__ wko, u16* __restrict__ wvo, u16* __restrict__ woo,
    uint32_t* __restrict__ mbytes, float qscale) {
  const int bid = blockIdx.x;
  const int tid = threadIdx.x;
  if (bid < 3072) {
    int seg = bid >> 10, sb = bid & 1023;
    const float* in = seg == 0 ? qa : seg == 1 ? ka : va;
    u16* out = seg == 0 ? qo : seg == 1 ? ko : vo;
    const int n4 = M_ * H_ / 4;
    for (int i = sb*256 + tid; i < n4; i += 1024*256) {
      float4 v = reinterpret_cast<const float4*>(in)[i];
      ushort4 o;
      o.x = f2bf(v.x); o.y = f2bf(v.y); o.z = f2bf(v.z); o.w = f2bf(v.w);
      reinterpret_cast<ushort4*>(out)[i] = o;
    }
  } else if (bid < 4096) {
    int seg = (bid - 3072) >> 8, sb = (bid - 3072) & 255;
    const float* in = seg == 0 ? Wq : seg == 1 ? Wk : seg == 2 ? Wv : Wo;
    u16* out = seg == 0 ? wqo : seg == 1 ? wko : seg == 2 ? wvo : woo;
    float sc = (seg == 0) ? qscale : 1.0f;
    const int n4 = H_ * H_ / 4;
    for (int i = sb*256 + tid; i < n4; i += 256*256) {
      float4 v = reinterpret_cast<const float4*>(in)[i];
      ushort4 o;
      o.x = f2bf(v.x * sc); o.y = f2bf(v.y * sc);
      o.z = f2bf(v.z * sc); o.w = f2bf(v.w * sc);
      reinterpret_cast<ushort4*>(out)[i] = o;
    }
  } else {
    // mask pack, gather: out dword index od is LINEAR (coalesced stores).
    // Layout [qblk][c][wave][hl][l31][j] — identical content to R12's buffer.
    int od = (bid - 4096)*256 + tid;                   // 0 .. B*S*512-1
    int j = od & 7, l31q = (od >> 3) & 31, hl = (od >> 8) & 1;
    int wv_ = (od >> 9) & 3, c = (od >> 11) & 31, qblk = od >> 16;
    int bq = qblk*128 + wv_*32 + l31q;
    int4 v = *reinterpret_cast<const int4*>(mask + (size_t)bq*2048 + c*64 + 4*hl + 8*(j & 3) + 32*(j >> 2));
    uint32_t w = (v.x != 0 ? 1u : 0u) | (v.y != 0 ? 0x100u : 0u) |
                 (v.z != 0 ? 0x10000u : 0u) | (v.w != 0 ? 0x1000000u : 0u);
    mbytes[od] = w;
  }
}

#define GLD16(gsrc, ldst) \
  __builtin_amdgcn_global_load_lds((const __attribute__((address_space(1))) void*)(gsrc), \
                                   (__attribute__((address_space(3))) void*)(ldst), 16, 0, 0)

// GEMM K-loop core, BK=64, XOR-swizzled LDS (pre-swizzled gload_lds source).
#define GEMM_KLOOP(A_, B_, As_, Bs_) \
  for (int k0 = 0; k0 < K; k0 += 64) { \
    const u16* Ab = (A_) + (size_t)m0 * K + k0; \
    const u16* Bb = (B_) + (size_t)n0 * K + k0; \
    _Pragma("unroll") \
    for (int i = 0; i < 4; i++) { \
      int idx = i*256 + tid; \
      int row = idx >> 3, q = idx & 7; \
      int qs = q ^ (row & 7); \
      char* la = (char*)(As_) + i*4096 + wave*1024; \
      char* lb = (char*)(Bs_) + i*4096 + wave*1024; \
      GLD16(Ab + (size_t)row*K + qs*8, la); \
      GLD16(Bb + (size_t)row*K + qs*8, lb); \
    } \
    __syncthreads(); \
    const int sa = (lo & 7) << 4; \
    _Pragma("unroll") \
    for (int kk = 0; kk < 2; kk++) { \
      bfrag af[4], bfv[4]; \
      _Pragma("unroll") \
      for (int t = 0; t < 4; t++) { \
        af[t]  = *reinterpret_cast<const bfrag*>((char*)(As_) + (wr*64 + t*16 + lo)*128 + ((kk*64 + hi*16) ^ sa)); \
        bfv[t] = *reinterpret_cast<const bfrag*>((char*)(Bs_) + (wc*64 + t*16 + lo)*128 + ((kk*64 + hi*16) ^ sa)); \
      } \
      _Pragma("unroll") \
      for (int mt = 0; mt < 4; mt++) \
        _Pragma("unroll") \
        for (int nt = 0; nt < 4; nt++) \
          acc[mt][nt] = __builtin_amdgcn_mfma_f32_16x16x32_bf16(af[mt], bfv[nt], acc[mt][nt], 0, 0, 0); \
    } \
    __syncthreads(); \
  }

// ---------------- Fused QKV projection GEMM ----------------
__global__ __launch_bounds__(256) void qkv_gemm(const u16* __restrict__ qa, const u16* __restrict__ ka,
                                                const u16* __restrict__ va,
                                                const u16* __restrict__ Wqb, const u16* __restrict__ Wkb,
                                                const u16* __restrict__ Wvb,
                                                const float* __restrict__ bqp, const float* __restrict__ bkp,
                                                const float* __restrict__ bvp, float qbscale,
                                                u16* __restrict__ qh, u16* __restrict__ kh,
                                                u16* __restrict__ vt) {
  constexpr int K = H_;
  __shared__ __align__(16) u16 SH[2][128*64];          // As / Bs, 16 KB each; SH[0] reused for V transpose
  u16* As = SH[0];
  u16* Bs = SH[1];
  const int tid = threadIdx.x;
  const int lane = tid & 63, wave = tid >> 6;
  const int lo = lane & 15, hi = lane >> 4;
  const int wr = wave >> 1, wc = wave & 1;
  const int wsel = blockIdx.y >> 3;
  const int m0 = blockIdx.x * 128, n0 = (blockIdx.y & 7) * 128;
  const u16* A  = wsel == 0 ? qa : wsel == 1 ? ka : va;
  const u16* Bm = wsel == 0 ? Wqb : wsel == 1 ? Wkb : Wvb;
  const float* bias = wsel == 0 ? bqp : wsel == 1 ? bkp : bvp;
  const float bscale = wsel == 0 ? qbscale : 1.0f;
  facc acc[4][4] = {};

  GEMM_KLOOP(A, Bm, As, Bs)

  if (wsel < 2) {
    u16* o = wsel == 0 ? qh : kh;
    #pragma unroll
    for (int nt = 0; nt < 4; nt++) {
      int n = n0 + wc*64 + nt*16 + lo;
      float bv = bias[n] * bscale;
      int hh = n >> 6, d = n & 63;
      #pragma unroll
      for (int mt = 0; mt < 4; mt++) {
        #pragma unroll
        for (int r = 0; r < 4; r++) {
          int m = m0 + wr*64 + mt*16 + hi*4 + r;
          int bb = m >> 11, s = m & (S_ - 1);
          o[(((size_t)bb*NH_ + hh)*S_ + s)*DK_ + d] = f2bf(acc[mt][nt][r] + bv);
        }
      }
    }
  } else {
    // V: tile -> LDS [64 d][128 s] (XOR-swizzled) -> coalesced d-major global writes.
    u16* scr = &SH[0][0];                     // 16 KB
    const int bb2 = m0 >> 11, s0r = m0 & (S_ - 1);
    #pragma unroll
    for (int p = 0; p < 2; p++) {            // head within n-range = wc
      __syncthreads();
      if (wc == p) {
        #pragma unroll
        for (int nt = 0; nt < 4; nt++) {
          int d = nt*16 + lo;
          float bv = bias[n0 + p*64 + d];
          #pragma unroll
          for (int mt = 0; mt < 4; mt++) {
            #pragma unroll
            for (int r = 0; r < 4; r++) {
              int s = wr*64 + mt*16 + hi*4 + r;
              *(u16*)((char*)scr + d*256 + ((s*2) ^ ((d & 7) << 4))) = f2bf(acc[mt][nt][r] + bv);
            }
          }
        }
      }
      __syncthreads();
      int hh = (n0 >> 6) + p;
      u16* vbase = vt + ((size_t)bb2*NH_ + hh) * DK_ * S_ + s0r;
      #pragma unroll
      for (int i = 0; i < 4; i++) {
        int idx = i*256 + tid;
        int d = idx >> 4, sc = idx & 15;
        bfrag v = *reinterpret_cast<const bfrag*>((char*)scr + d*256 + ((sc*16) ^ ((d & 7) << 4)));
        *reinterpret_cast<bfrag*>(vbase + (size_t)d*S_ + sc*8) = v;
      }
    }
  }
}

// ---------------- Output projection GEMM: out = xb @ Wo^T + bo (f32) ----------------
__global__ __launch_bounds__(256) void gemm_out(const u16* __restrict__ A, const u16* __restrict__ Bm,
                                                const float* __restrict__ bias, float* __restrict__ o) {
  constexpr int K = H_, N = H_;
  __shared__ __align__(16) u16 As[128*64];
  __shared__ __align__(16) u16 Bs[128*64];
  const int tid = threadIdx.x;
  const int lane = tid & 63, wave = tid >> 6;
  const int lo = lane & 15, hi = lane >> 4;
  const int wr = wave >> 1, wc = wave & 1;
  const int m0 = blockIdx.x * 128, n0 = blockIdx.y * 128;
  facc acc[4][4] = {};

  GEMM_KLOOP(A, Bm, As, Bs)

  #pragma unroll
  for (int nt = 0; nt < 4; nt++) {
    int n = n0 + wc*64 + nt*16 + lo;
    float bv = bias[n];
    #pragma unroll
    for (int mt = 0; mt < 4; mt++) {
      #pragma unroll
      for (int r = 0; r < 4; r++) {
        int m = m0 + wr*64 + mt*16 + hi*4 + r;
        o[(size_t)m*N + n] = acc[mt][nt][r] + bv;
      }
    }
  }
}

// ---------------- Flash attention v7c: fixed-M softmax, coalesced mask reads ----------------
__global__ __launch_bounds__(256, 4) void attn_kernel(const u16* __restrict__ Qh, const u16* __restrict__ Kh,
                                                      const u16* __restrict__ Vt, const uint32_t* __restrict__ mbytes,
                                                      u16* __restrict__ xout) {
  __shared__ __align__(16) u16 Ks[2][64*64];   // 8 KiB each, XOR-swizzled rows of 128 B
  __shared__ __align__(16) u16 Vs[2][64*64];
  const int tid = threadIdx.x;
  const int lane = tid & 63, wave = tid >> 6;
  const int l31 = lane & 31, hl = lane >> 5;
  const int gid = blockIdx.x;                  // XCD-bijective swizzle: 8 bh per XCD, qt inner
  const int bh = (gid & 7) * 8 + (gid >> 7);
  const int qt = (gid >> 3) & 15;
  const int b = bh >> 4, hd = bh & 15;
  const int q0 = qt * 128;
  const size_t bhS = (size_t)bh * S_;
  const int swz = (lane & 7) << 4;

  bfrag qf[4];
  {
    const u16* qrow = Qh + (bhS + q0 + wave*32 + l31) * DK_;
    #pragma unroll
    for (int t = 0; t < 4; t++) qf[t] = *reinterpret_cast<const bfrag*>(qrow + t*16 + hl*8);
  }
  // coalesced mask base: [qblk][c][wave][hl][l31][32B]; wave's chunk-read = contiguous 2 KB
  const int qblk = b*16 + qt;
  const char* mrowb = (const char*)mbytes + (size_t)qblk*262144 + wave*2048 + hl*1024 + l31*32;

  const int srow = wave*8 + (lane >> 3);
  const int scol = ((lane & 7) ^ (lane >> 3)) * 16;
  const char* ksrc = (const char*)(Kh + bhS * DK_) + (size_t)srow * 128 + scol;
  const char* vsrc = (const char*)(Vt + (size_t)bh * DK_ * S_) + (size_t)srow * (S_*2) + scol;

#define STAGE(buf, c) { \
    char* kl = (char*)Ks[buf] + wave*1024; \
    char* vl = (char*)Vs[buf] + wave*1024; \
    GLD16(ksrc + (size_t)(c)*8192,          kl); \
    GLD16(ksrc + (size_t)(c)*8192 + 4096,   kl + 4096); \
    GLD16(vsrc + (size_t)(c)*128,           vl); \
    GLD16(vsrc + (size_t)(c)*128 + 131072,  vl + 4096); \
  }

  float l_run = 0.f;                           // per-half-lane partial denominator
  f32x16 accO[2];
  #pragma unroll
  for (int e = 0; e < 16; e++) { accO[0][e] = 0.f; accO[1][e] = 0.f; }

  STAGE(0, 0);
  u32x4 mA_cur = *reinterpret_cast<const u32x4*>(mrowb);
  u32x4 mB_cur = *reinterpret_cast<const u32x4*>(mrowb + 16);
  __syncthreads();

  for (int c = 0; c < 32; c++) {
    const int cur = c & 1;
    if (c + 1 < 32) STAGE(cur ^ 1, c + 1);

    u32x4 mA = mA_cur, mB = mB_cur;
    if (c + 1 < 32) {
      const char* mn = mrowb + (size_t)(c + 1)*8192;
      mA_cur = *reinterpret_cast<const u32x4*>(mn);
      mB_cur = *reinterpret_cast<const u32x4*>(mn + 16);
    }

    // ---- C-init = -M - 1e36*maskbyte ----
    f32x16 s0, s1;
    #pragma unroll
    for (int r = 0; r < 16; r++) {
      float f0 = (float)((mA[r >> 2] >> ((r & 3) * 8)) & 0xffu);
      float f1 = (float)((mB[r >> 2] >> ((r & 3) * 8)) & 0xffu);
      s0[r] = __builtin_fmaf(f0, -1e36f, -8.0f);
      s1[r] = __builtin_fmaf(f1, -1e36f, -8.0f);
    }

    // ---- QK^T swapped ----
    const char* KsB = (const char*)Ks[cur];
    __builtin_amdgcn_s_setprio(1);
    #pragma unroll
    for (int t = 0; t < 4; t++) {
      bfrag k0 = *reinterpret_cast<const bfrag*>(KsB + l31*128        + ((t*32 + hl*16) ^ swz));
      bfrag k1 = *reinterpret_cast<const bfrag*>(KsB + (32 + l31)*128 + ((t*32 + hl*16) ^ swz));
      s0 = __builtin_amdgcn_mfma_f32_32x32x16_bf16(k0, qf[t], s0, 0, 0, 0);
      s1 = __builtin_amdgcn_mfma_f32_32x32x16_bf16(k1, qf[t], s1, 0, 0, 0);
    }
    __builtin_amdgcn_s_setprio(0);

    // ---- p = 2^s directly ----
    #pragma unroll
    for (int r = 0; r < 16; r++) {
      s0[r] = __builtin_amdgcn_exp2f(s0[r]);
      s1[r] = __builtin_amdgcn_exp2f(s1[r]);
    }
    float a8[8];
    #pragma unroll
    for (int r = 0; r < 8; r++) a8[r] = (s0[r] + s0[r+8]) + (s1[r] + s1[r+8]);
    l_run += ((a8[0] + a8[1]) + (a8[2] + a8[3])) + ((a8[4] + a8[5]) + (a8[6] + a8[7]));

    // ---- P -> PV A-frags in-register ----
    u32x4 pa[4];
    #pragma unroll
    for (int kt = 0; kt < 2; kt++) {
      uint32_t W[8];
      #pragma unroll
      for (int j = 0; j < 8; j++)
        W[j] = kt == 0 ? cvtpk_bf16(s0[2*j], s0[2*j+1]) : cvtpk_bf16(s1[2*j], s1[2*j+1]);
      u32x2 r02 = __builtin_amdgcn_permlane32_swap(W[0], W[2], false, false);
      u32x2 r13 = __builtin_amdgcn_permlane32_swap(W[1], W[3], false, false);
      u32x2 r46 = __builtin_amdgcn_permlane32_swap(W[4], W[6], false, false);
      u32x2 r57 = __builtin_amdgcn_permlane32_swap(W[5], W[7], false, false);
      pa[kt*2    ][0] = r02[0]; pa[kt*2    ][1] = r13[0]; pa[kt*2    ][2] = r02[1]; pa[kt*2    ][3] = r13[1];
      pa[kt*2 + 1][0] = r46[0]; pa[kt*2 + 1][1] = r57[0]; pa[kt*2 + 1][2] = r46[1]; pa[kt*2 + 1][3] = r57[1];
    }

    // ---- PV ----
    const char* VsB = (const char*)Vs[cur];
    __builtin_amdgcn_s_setprio(1);
    #pragma unroll
    for (int ks = 0; ks < 4; ks++) {
      bfrag pb = __builtin_bit_cast(bfrag, pa[ks]);
      bfrag v0 = *reinterpret_cast<const bfrag*>(VsB + l31*128        + ((ks*32 + hl*16) ^ swz));
      bfrag v1 = *reinterpret_cast<const bfrag*>(VsB + (32 + l31)*128 + ((ks*32 + hl*16) ^ swz));
      accO[0] = __builtin_amdgcn_mfma_f32_32x32x16_bf16(v0, pb, accO[0], 0, 0, 0);
      accO[1] = __builtin_amdgcn_mfma_f32_32x32x16_bf16(v1, pb, accO[1], 0, 0, 0);
    }
    __builtin_amdgcn_s_setprio(0);
    __syncthreads();
  }
#undef STAGE

  // ---- finalize ----
  float l_tot = l_run + __shfl_xor(l_run, 32);
  float linv = (l_tot > 0.f) ? (1.f / l_tot) : 0.f;
  u16* Xs = (u16*)Ks;
  {
    char* xb = (char*)Xs + (wave*32 + l31) * 128;
    #pragma unroll
    for (int dt = 0; dt < 2; dt++)
      #pragma unroll
      for (int j = 0; j < 8; j++) {
        uint32_t w = cvtpk_bf16(accO[dt][2*j] * linv, accO[dt][2*j+1] * linv);
        int d = dt*32 + ((2*j) & 3) + 8*((2*j) >> 2) + 4*hl;
        *reinterpret_cast<uint32_t*>(xb + ((d*2) ^ swz)) = w;
      }
  }
  __syncthreads();
  {
    int row = tid >> 1, d0 = (tid & 1) * 32;
    int rsw = (row & 7) << 4;
    u16* orow = xout + ((size_t)b * S_ + q0 + row) * H_ + hd * DK_ + d0;
    #pragma unroll
    for (int i = 0; i < 4; i++) {
      bfrag v = *reinterpret_cast<const bfrag*>((char*)Xs + row*128 + ((d0*2 + i*16) ^ rsw));
      *reinterpret_cast<bfrag*>((char*)orow + i*16) = v;
    }
  }
}

// ---------------- launch ----------------
extern "C" void kernel_launch(void* const* d_in, const int* in_sizes, int n_in,
                              void* d_out, int out_size, void* d_ws, size_t ws_size,
                              hipStream_t stream) {
  const float* query = (const float*)d_in[0];
  const float* key_  = (const float*)d_in[1];
  const float* value = (const float*)d_in[2];
  const int*   mask  = (const int*)d_in[3];
  const float* Wq = (const float*)d_in[4];
  const float* bq = (const float*)d_in[5];
  const float* Wk = (const float*)d_in[6];
  const float* bk = (const float*)d_in[7];
  const float* Wv = (const float*)d_in[8];
  const float* bv = (const float*)d_in[9];
  const float* Wo = (const float*)d_in[10];
  const float* bo = (const float*)d_in[11];
  float* out = (float*)d_out;

  char* ws = (char*)d_ws;
  const size_t MB = 1024 * 1024;
  u16* q_act = (u16*)(ws + 0*MB);
  u16* k_act = (u16*)(ws + 16*MB);
  u16* v_act = (u16*)(ws + 32*MB);
  u16* wq_b  = (u16*)(ws + 48*MB);
  u16* wk_b  = (u16*)(ws + 50*MB);
  u16* wv_b  = (u16*)(ws + 52*MB);
  u16* wo_b  = (u16*)(ws + 54*MB);
  u16* qh    = (u16*)(ws + 56*MB);
  u16* kh    = (u16*)(ws + 72*MB);
  u16* vt    = (u16*)(ws + 104*MB);
  u16* xb    = (u16*)(ws + 120*MB);
  uint32_t* mbytes = (uint32_t*)(ws + 136*MB);   // 16.8 MiB mask bytes (coalesced layout)

  const float QSCALE = 0.125f * 1.44269504088896f;   // 1/sqrt(DK) * log2(e), folded into Wq/bq

  prep_kernel<<<20480, 256, 0, stream>>>(query, key_, value, Wq, Wk, Wv, Wo, mask,
                                         q_act, k_act, v_act, wq_b, wk_b, wv_b, wo_b,
                                         mbytes, QSCALE);

  qkv_gemm<<<dim3(M_/128, 24), 256, 0, stream>>>(q_act, k_act, v_act, wq_b, wk_b, wv_b,
                                                 bq, bk, bv, QSCALE, qh, kh, vt);
  attn_kernel<<<1024, 256, 0, stream>>>(qh, kh, vt, mbytes, xb);
  gemm_out<<<dim3(M_/128, H_/128), 256, 0, stream>>>(xb, wo_b, bo, out);
}